// Round 4
// baseline (3567.211 us; speedup 1.0000x reference)
//
#include <hip/hip_runtime.h>
#include <cstdint>
#include <cstddef>

// ---------------------------------------------------------------------------
// Gemma 2-layer forward, MI355X. Round 4: register-pipelined GEMM with the
//   tail-drain race FIXED (vmcnt(4) only while stage(t+3) is issued; vmcnt(0)
//   in the 3 tail iterations). Otherwise identical to round 3.
// ---------------------------------------------------------------------------

typedef unsigned short u16;
typedef __bf16 bf16x8 __attribute__((ext_vector_type(8)));
typedef float f32x4 __attribute__((ext_vector_type(4)));

#define S_LEN 2048
#define HDIM  2048
#define NHEAD 8
#define HD    256
#define QKV_N 2560
#define ATT_SCALE 0.0625f

__device__ __forceinline__ u16 f2b(float f) {
  union { float f; unsigned u; } x; x.f = f;
  unsigned r = x.u + 0x7FFFu + ((x.u >> 16) & 1u);
  return (u16)(r >> 16);
}
__device__ __forceinline__ float b2f(u16 b) {
  union { unsigned u; float f; } x; x.u = ((unsigned)b) << 16;
  return x.f;
}

typedef __attribute__((address_space(1))) void as1_void;
typedef __attribute__((address_space(3))) void as3_void;
__device__ __forceinline__ void gload_lds16(const void* g, void* l) {
  __builtin_amdgcn_global_load_lds((as1_void*)((void*)g), (as3_void*)l, 16, 0, 0);
}

__device__ __forceinline__ void barrier_raw() {
  __builtin_amdgcn_sched_barrier(0);
  asm volatile("" ::: "memory");
  __builtin_amdgcn_s_barrier();
  asm volatile("" ::: "memory");
  __builtin_amdgcn_sched_barrier(0);
}

__device__ __forceinline__ float gelu_tanh(float x) {
  float t = tanhf(0.7978845608028654f * (x + 0.044715f * x * x * x));
  return 0.5f * x * (1.0f + t);
}

// ---------------------------------------------------------------------------
// f32 -> bf16 conversion (vectorized grid-stride)
// ---------------------------------------------------------------------------
__global__ void cvt_kernel(const float* __restrict__ in, u16* __restrict__ out, int n4) {
  int idx = blockIdx.x * blockDim.x + threadIdx.x;
  int stride = gridDim.x * blockDim.x;
  for (int i = idx; i < n4; i += stride) {
    f32x4 v = reinterpret_cast<const f32x4*>(in)[i];
    unsigned lo = (unsigned)f2b(v[0]) | ((unsigned)f2b(v[1]) << 16);
    unsigned hi = (unsigned)f2b(v[2]) | ((unsigned)f2b(v[3]) << 16);
    uint2 p; p.x = lo; p.y = hi;
    reinterpret_cast<uint2*>(out)[i] = p;
  }
}

// ---------------------------------------------------------------------------
// RMSNorm: one block per row (H=2048, 256 thr * 8 elems). f32 math.
// ---------------------------------------------------------------------------
template<bool OBF>
__launch_bounds__(256)
__global__ void rms_kernel(const float* in, const float* w, u16* obf, float* of) {
  const int row = blockIdx.x;
  const int tid = threadIdx.x;
  const float* x = in + (size_t)row * HDIM;
  f32x4 v0 = reinterpret_cast<const f32x4*>(x)[tid];
  f32x4 v1 = reinterpret_cast<const f32x4*>(x)[tid + 256];
  float ss = v0[0]*v0[0] + v0[1]*v0[1] + v0[2]*v0[2] + v0[3]*v0[3]
           + v1[0]*v1[0] + v1[1]*v1[1] + v1[2]*v1[2] + v1[3]*v1[3];
#pragma unroll
  for (int off = 32; off > 0; off >>= 1) ss += __shfl_xor(ss, off);
  __shared__ float sred[4];
  if ((tid & 63) == 0) sred[tid >> 6] = ss;
  __syncthreads();
  float tot = sred[0] + sred[1] + sred[2] + sred[3];
  float r = rsqrtf(tot * (1.0f / (float)HDIM) + 1e-6f);
  f32x4 w0 = reinterpret_cast<const f32x4*>(w)[tid];
  f32x4 w1 = reinterpret_cast<const f32x4*>(w)[tid + 256];
#pragma unroll
  for (int j = 0; j < 4; ++j) {
    float a = v0[j] * r * (1.0f + w0[j]);
    float b = v1[j] * r * (1.0f + w1[j]);
    if (OBF) {
      obf[(size_t)row * HDIM + tid * 4 + j]        = f2b(a);
      obf[(size_t)row * HDIM + 1024 + tid * 4 + j] = f2b(b);
    } else {
      of[(size_t)row * HDIM + tid * 4 + j]        = a;
      of[(size_t)row * HDIM + 1024 + tid * 4 + j] = b;
    }
  }
}

// ---------------------------------------------------------------------------
// GEMM  C[M,N] = A[M,K] * B[N,K]^T  (bf16 in, f32 acc)
// 256x256 tile, BK=32, 8 waves (2Mx4N), 4-buffer LDS ring (128 KiB),
// register ping-pong frag prefetch (tile t+1 read during tile t's MFMA),
// counted vmcnt(4) while stage(t+3) exists, vmcnt(0) in the tail (RACE FIX),
// one raw barrier per K-tile, XOR LDS swizzle, pre-swizzled gload_lds sources,
// setprio clusters, bijective XCD swizzle.
// EPI 0: Cb=bf16   1: Cf+=acc   2: Cb=gelu(Cb)*acc   3: Cf[z*M*N+idx]=acc
// Requires M%256==0, N%256==0, Ks%64==0 (NT even), lda/ldb%8==0.
//
// Pipeline safety invariants (all verified):
//  - end of body t (steady): outstanding = {stage(t+1),(t+2),(t+3)}; vmcnt(4)
//    => stage(t+2) landed => body t+1's prefetch of tile t+2 reads valid LDS.
//  - t=NT-3: stage skipped => outstanding={stage(NT-2),(NT-1)}; must use
//    vmcnt(0) so body NT-2's prefetch of tile NT-1 is safe.  <-- round-3 bug
//  - WAR: stage(t+3) writes buf (t-1)&3; all waves' reads of that buf
//    completed before their body-(t-1) MFMA (compiler lgkm waits), hence
//    before the end-of-(t-1) barrier, which precedes this stage.
// ---------------------------------------------------------------------------
#define GEMM_BODY(T, RA, RB, RAN, RBN)                                         \
  {                                                                            \
    const int t_ = (T);                                                        \
    const char* bnxt_ = smem + (((t_ + 1) & 3) << 15);                         \
    if (t_ + 1 < NT) {                                                         \
      _Pragma("unroll")                                                        \
      for (int mf = 0; mf < 4; ++mf)                                           \
        RAN[mf] = *reinterpret_cast<const bf16x8*>(bnxt_ + aoff[mf]);          \
      _Pragma("unroll")                                                        \
      for (int nf = 0; nf < 4; ++nf)                                           \
        RBN[nf] = *reinterpret_cast<const bf16x8*>(bnxt_ + boff[nf]);          \
    }                                                                          \
    __builtin_amdgcn_s_setprio(1);                                             \
    _Pragma("unroll")                                                          \
    for (int mf = 0; mf < 4; ++mf)                                             \
      _Pragma("unroll")                                                        \
      for (int nf = 0; nf < 4; ++nf)                                           \
        acc[mf][nf] = __builtin_amdgcn_mfma_f32_16x16x32_bf16(RA[mf], RB[nf], acc[mf][nf], 0, 0, 0); \
    __builtin_amdgcn_s_setprio(0);                                             \
    if (t_ + 1 < NT) {                                                         \
      _Pragma("unroll")                                                        \
      for (int mf = 4; mf < 8; ++mf)                                           \
        RAN[mf] = *reinterpret_cast<const bf16x8*>(bnxt_ + aoff[mf]);          \
    }                                                                          \
    __builtin_amdgcn_s_setprio(1);                                             \
    _Pragma("unroll")                                                          \
    for (int mf = 4; mf < 8; ++mf)                                             \
      _Pragma("unroll")                                                        \
      for (int nf = 0; nf < 4; ++nf)                                           \
        acc[mf][nf] = __builtin_amdgcn_mfma_f32_16x16x32_bf16(RA[mf], RB[nf], acc[mf][nf], 0, 0, 0); \
    __builtin_amdgcn_s_setprio(0);                                             \
    if (t_ + 3 < NT) {                                                         \
      stage(t_ + 3);                                                           \
      asm volatile("s_waitcnt vmcnt(4)" ::: "memory");                         \
    } else {                                                                   \
      asm volatile("s_waitcnt vmcnt(0)" ::: "memory");                         \
    }                                                                          \
    barrier_raw();                                                             \
  }

template<int EPI>
__launch_bounds__(512, 2)
__global__ void gemm256(const u16* __restrict__ A, const u16* __restrict__ B,
                        u16* Cb, float* Cf, int M, int N, int Ks,
                        int lda, int ldb, int ldc) {
  extern __shared__ char smem[];   // 4 bufs x 32 KiB: [A 16K | B 16K] each
  const int tid = threadIdx.x;
  const int lane = tid & 63, w = tid >> 6;
  const int l16 = lane & 15, lhi = lane >> 4;
  const int wr = w >> 2, wc = w & 3;

  // bijective XCD swizzle (m204), column-major tile map (B-panel L2 reuse)
  const int nwg = gridDim.x, bid = blockIdx.x;
  const int q = nwg >> 3, rm = nwg & 7, xc = bid & 7, li = bid >> 3;
  const int swz = (xc < rm ? xc * (q + 1) : rm * (q + 1) + (xc - rm) * q) + li;
  const int MT = M >> 8;
  const int m0 = (swz % MT) << 8;
  const int n0 = (swz / MT) << 8;

  const int kbase = blockIdx.z * Ks;
  const int NT = Ks >> 5;

  // pre-swizzled per-lane global sources (LDS dest = wave-uniform + lane*16):
  // linear LDS byte o: row r = o>>6, lds-slot s = (o>>4)&3, global k-slot = s ^ ((r>>1)&3)
  const u16 *srcA0, *srcA1, *srcB0, *srcB1;
  {
    int o0 = w * 2048 + lane * 16;
    int o1 = o0 + 1024;
    int r0 = o0 >> 6, s0 = ((o0 >> 4) & 3) ^ ((r0 >> 1) & 3);
    int r1 = o1 >> 6, s1 = ((o1 >> 4) & 3) ^ ((r1 >> 1) & 3);
    srcA0 = A + (size_t)(m0 + r0) * lda + kbase + s0 * 8;
    srcA1 = A + (size_t)(m0 + r1) * lda + kbase + s1 * 8;
    srcB0 = B + (size_t)(n0 + r0) * ldb + kbase + s0 * 8;
    srcB1 = B + (size_t)(n0 + r1) * ldb + kbase + s1 * 8;
  }
  const int stA = w * 2048;   // wave-uniform LDS dest base (lane*16 implicit)

  auto stage = [&](int t) {
    char* bb = smem + ((t & 3) << 15);
    const int ko = t * 32;
    gload_lds16(srcA0 + ko, bb + stA);
    gload_lds16(srcA1 + ko, bb + stA + 1024);
    gload_lds16(srcB0 + ko, bb + 16384 + stA);
    gload_lds16(srcB1 + ko, bb + 16384 + stA + 1024);
  };

  // swizzled frag read offsets (within a buffer): row*64 + (lhi ^ ((l16>>1)&3))*16
  int aoff[8], boff[4];
  const int sx = (lhi ^ ((l16 >> 1) & 3)) << 4;
#pragma unroll
  for (int mf = 0; mf < 8; ++mf)
    aoff[mf] = (wr * 128 + mf * 16 + l16) * 64 + sx;
#pragma unroll
  for (int nf = 0; nf < 4; ++nf)
    boff[nf] = 16384 + (wc * 64 + nf * 16 + l16) * 64 + sx;

  f32x4 acc[8][4] = {};

  // prologue: stage tiles 0..2; vmcnt(4) => tiles 0,1 landed (tile 2 in flight)
  stage(0);
  if (1 < NT) stage(1);
  if (2 < NT) stage(2);
  asm volatile("s_waitcnt vmcnt(4)" ::: "memory");
  barrier_raw();

  bf16x8 rA[8], rB[4], rAn[8], rBn[4];
#pragma unroll
  for (int mf = 0; mf < 8; ++mf) rA[mf] = *reinterpret_cast<const bf16x8*>(smem + aoff[mf]);
#pragma unroll
  for (int nf = 0; nf < 4; ++nf) rB[nf] = *reinterpret_cast<const bf16x8*>(smem + boff[nf]);

  for (int t = 0; t < NT; t += 2) {
    GEMM_BODY(t,     rA,  rB,  rAn, rBn);
    GEMM_BODY(t + 1, rAn, rBn, rA,  rB);
  }

#pragma unroll
  for (int mf = 0; mf < 8; ++mf)
#pragma unroll
    for (int nf = 0; nf < 4; ++nf)
#pragma unroll
      for (int rr = 0; rr < 4; ++rr) {
        int row = m0 + wr * 128 + mf * 16 + lhi * 4 + rr;
        int col = n0 + wc * 64 + nf * 16 + l16;
        size_t idx = (size_t)row * ldc + col;
        float v = acc[mf][nf][rr];
        if (EPI == 0)      Cb[idx] = f2b(v);
        else if (EPI == 1) Cf[idx] += v;
        else if (EPI == 2) { float g = b2f(Cb[idx]); Cb[idx] = f2b(gelu_tanh(g) * v); }
        else               Cf[(size_t)blockIdx.z * ((size_t)M * N) + idx] = v;
      }
}

// h += p0 + p1 (split-K combine), f32x4 grid-stride
__global__ void combine_kernel(float* __restrict__ h, const float* __restrict__ p0,
                               const float* __restrict__ p1, int n4) {
  int idx = blockIdx.x * blockDim.x + threadIdx.x;
  int stride = gridDim.x * blockDim.x;
  for (int i = idx; i < n4; i += stride) {
    f32x4 a = reinterpret_cast<f32x4*>(h)[i];
    f32x4 b = reinterpret_cast<const f32x4*>(p0)[i];
    f32x4 c = reinterpret_cast<const f32x4*>(p1)[i];
    a = a + b + c;
    reinterpret_cast<f32x4*>(h)[i] = a;
  }
}

// ---------------------------------------------------------------------------
// RoPE in place on fused qkv buffer [4096][2560]
// ---------------------------------------------------------------------------
__global__ void rope_kernel(u16* qkv, const float* __restrict__ cosT, const float* __restrict__ sinT) {
  const int s = blockIdx.x, b = blockIdx.y;
  const size_t base = (size_t)(b * S_LEN + s) * QKV_N;
  for (int i = threadIdx.x; i < 9 * 128; i += 256) {
    int hh = i >> 7, d = i & 127;
    size_t off = base + (hh < 8 ? hh * 256 : 2048) + d;
    float x1 = b2f(qkv[off]), x2 = b2f(qkv[off + 128]);
    float c = cosT[s * 128 + d], sn = sinT[s * 128 + d];
    qkv[off]       = f2b(x1 * c - x2 * sn);
    qkv[off + 128] = f2b(x1 * sn + x2 * c);
  }
}

// ---------------------------------------------------------------------------
// V transpose: vT[b][d][s] <- qkv[b*S+s][2304+d]
// ---------------------------------------------------------------------------
__global__ void vtrans_kernel(const u16* __restrict__ qkv, u16* __restrict__ vT) {
  __shared__ u16 t[64][65];
  const int s0 = blockIdx.x * 64, d0 = blockIdx.y * 64, b = blockIdx.z;
  for (int i = threadIdx.x; i < 4096; i += 256) {
    int r = i >> 6, c = i & 63;
    t[r][c] = qkv[(size_t)(b * S_LEN + s0 + r) * QKV_N + 2304 + d0 + c];
  }
  __syncthreads();
  for (int i = threadIdx.x; i < 4096; i += 256) {
    int r = i >> 6, c = i & 63;
    vT[(size_t)(b * HD + d0 + r) * S_LEN + s0 + c] = t[c][r];
  }
}

// ---------------------------------------------------------------------------
// Causal flash attention (MQA, NKV=1), 64 q-rows/block, 4 waves.
// ---------------------------------------------------------------------------
__launch_bounds__(256)
__global__ void flash_kernel(const u16* __restrict__ qkv, const u16* __restrict__ vT,
                             u16* __restrict__ outp) {
  const int qt = blockIdx.x, hh = blockIdx.y, b = blockIdx.z;
  const int tid = threadIdx.x, lane = tid & 63, w = tid >> 6;
  const int l16 = lane & 15, lhi = lane >> 4;
  __shared__ alignas(16) u16 p_lds[4][16][64];

  bf16x8 aq[8];
  {
    const u16* qp = qkv + (size_t)(b * S_LEN + qt * 64 + w * 16 + l16) * QKV_N + hh * HD + lhi * 8;
#pragma unroll
    for (int kf = 0; kf < 8; ++kf)
      aq[kf] = *reinterpret_cast<const bf16x8*>(qp + kf * 32);
  }
  f32x4 oacc[16] = {};
  float mrow[4] = {-1e30f, -1e30f, -1e30f, -1e30f};
  float lrow[4] = {0.f, 0.f, 0.f, 0.f};
  const int rowg0 = qt * 64 + w * 16 + lhi * 4;

  const int ntiles = qt + 1;
  for (int t = 0; t < ntiles; ++t) {
    const int j0 = t * 64;
    f32x4 sacc[4] = {};
    {
      const u16* kb = qkv + (size_t)(b * S_LEN + j0) * QKV_N + HDIM + lhi * 8;
#pragma unroll
      for (int nf = 0; nf < 4; ++nf) {
        const u16* kp = kb + (size_t)(nf * 16 + l16) * QKV_N;
#pragma unroll
        for (int kf = 0; kf < 8; ++kf) {
          bf16x8 bk = *reinterpret_cast<const bf16x8*>(kp + kf * 32);
          sacc[nf] = __builtin_amdgcn_mfma_f32_16x16x32_bf16(aq[kf], bk, sacc[nf], 0, 0, 0);
        }
      }
    }
    float sval[4][4];
    float tm[4] = {-1e30f, -1e30f, -1e30f, -1e30f};
#pragma unroll
    for (int nf = 0; nf < 4; ++nf) {
      int colg = j0 + nf * 16 + l16;
#pragma unroll
      for (int r = 0; r < 4; ++r) {
        float sv = sacc[nf][r] * ATT_SCALE;
        if (colg > rowg0 + r) sv = -1e30f;
        sval[nf][r] = sv;
        tm[r] = fmaxf(tm[r], sv);
      }
    }
#pragma unroll
    for (int off = 1; off < 16; off <<= 1)
#pragma unroll
      for (int r = 0; r < 4; ++r) tm[r] = fmaxf(tm[r], __shfl_xor(tm[r], off));

    float alpha[4], psum[4] = {0.f, 0.f, 0.f, 0.f};
#pragma unroll
    for (int r = 0; r < 4; ++r) {
      float mn = fmaxf(mrow[r], tm[r]);
      alpha[r] = __expf(mrow[r] - mn);
      mrow[r] = mn;
    }
#pragma unroll
    for (int nf = 0; nf < 4; ++nf)
#pragma unroll
      for (int r = 0; r < 4; ++r) {
        float p = __expf(sval[nf][r] - mrow[r]);
        psum[r] += p;
        p_lds[w][lhi * 4 + r][nf * 16 + l16] = f2b(p);
      }
#pragma unroll
    for (int off = 1; off < 16; off <<= 1)
#pragma unroll
      for (int r = 0; r < 4; ++r) psum[r] += __shfl_xor(psum[r], off);
#pragma unroll
    for (int r = 0; r < 4; ++r) lrow[r] = lrow[r] * alpha[r] + psum[r];
#pragma unroll
    for (int nf2 = 0; nf2 < 16; ++nf2)
#pragma unroll
      for (int r = 0; r < 4; ++r) oacc[nf2][r] *= alpha[r];

#pragma unroll
    for (int kf2 = 0; kf2 < 2; ++kf2) {
      bf16x8 pa = *reinterpret_cast<const bf16x8*>(&p_lds[w][l16][kf2 * 32 + lhi * 8]);
      const u16* vb = vT + (size_t)(b * HD + l16) * S_LEN + j0 + kf2 * 32 + lhi * 8;
#pragma unroll
      for (int nf2 = 0; nf2 < 16; ++nf2) {
        bf16x8 bv = *reinterpret_cast<const bf16x8*>(vb + (size_t)(nf2 * 16) * S_LEN);
        oacc[nf2] = __builtin_amdgcn_mfma_f32_16x16x32_bf16(pa, bv, oacc[nf2], 0, 0, 0);
      }
    }
  }

  float inv[4];
#pragma unroll
  for (int r = 0; r < 4; ++r) inv[r] = 1.0f / lrow[r];
#pragma unroll
  for (int nf2 = 0; nf2 < 16; ++nf2)
#pragma unroll
    for (int r = 0; r < 4; ++r) {
      size_t idx = (size_t)(b * S_LEN + rowg0 + r) * HDIM + hh * HD + nf2 * 16 + l16;
      outp[idx] = f2b(oacc[nf2][r] * inv[r]);
    }
}

// ---------------------------------------------------------------------------
// Host orchestration
// ---------------------------------------------------------------------------
extern "C" void kernel_launch(void* const* d_in, const int* in_sizes, int n_in,
                              void* d_out, int out_size, void* d_ws, size_t ws_size,
                              hipStream_t stream) {
  const float* hidden = (const float*)d_in[0];
  const float* cosT   = (const float*)d_in[1];
  const float* sinT   = (const float*)d_in[2];
  const float* wq  = (const float*)d_in[6];
  const float* wk  = (const float*)d_in[7];
  const float* wv  = (const float*)d_in[8];
  const float* wo  = (const float*)d_in[9];
  const float* wg  = (const float*)d_in[10];
  const float* wu  = (const float*)d_in[11];
  const float* wd  = (const float*)d_in[12];
  const float* ln1 = (const float*)d_in[13];
  const float* ln2 = (const float*)d_in[14];
  const float* nw  = (const float*)d_in[15];
  float* h = (float*)d_out;

  // ws layout (u16 elems): W 67.1M | xbf 8.4M | qkv 10.5M | vT 1.05M | attno 8.4M | gate 67.1M
  u16* W     = (u16*)d_ws;
  u16* xbf   = W + 67108864ull;
  u16* qkv   = xbf + 8388608ull;
  u16* vTb   = qkv + 10485760ull;
  u16* attno = vTb + 1048576ull;
  u16* gateb = attno + 8388608ull;
  float* pbuf = (float*)(W + 33554432ull);  // split-K partials (2 x 8.4M f32), 2nd half of W

  hipFuncSetAttribute(reinterpret_cast<const void*>(gemm256<0>), hipFuncAttributeMaxDynamicSharedMemorySize, 131072);
  hipFuncSetAttribute(reinterpret_cast<const void*>(gemm256<1>), hipFuncAttributeMaxDynamicSharedMemorySize, 131072);
  hipFuncSetAttribute(reinterpret_cast<const void*>(gemm256<2>), hipFuncAttributeMaxDynamicSharedMemorySize, 131072);
  hipFuncSetAttribute(reinterpret_cast<const void*>(gemm256<3>), hipFuncAttributeMaxDynamicSharedMemorySize, 131072);

  hipMemcpyAsync(h, hidden, sizeof(float) * 8388608ull, hipMemcpyDeviceToDevice, stream);

  auto cvt = [&](const float* src, u16* dst, long n) {
    int n4 = (int)(n >> 2);
    int blocks = (n4 + 255) / 256;
    if (blocks > 2048) blocks = 2048;
    cvt_kernel<<<blocks, 256, 0, stream>>>(src, dst, n4);
  };

  for (int l = 0; l < 2; ++l) {
    const float* lwq = wq + (size_t)l * 2048 * 2048;
    const float* lwk = wk + (size_t)l * 256 * 2048;
    const float* lwv = wv + (size_t)l * 256 * 2048;
    const float* lwo = wo + (size_t)l * 2048 * 2048;
    const float* lwg = wg + (size_t)l * 16384 * 2048;
    const float* lwu = wu + (size_t)l * 16384 * 2048;
    const float* lwd = wd + (size_t)l * 2048 * 16384;

    // x = rms(h, ln1)
    rms_kernel<true><<<4096, 256, 0, stream>>>(h, ln1 + l * 2048, xbf, nullptr);

    // fused qkv projection: W rows = [wq(2048) | wk(256) | wv(256)]
    cvt(lwq, W, 4194304);
    cvt(lwk, W + 4194304, 524288);
    cvt(lwv, W + 4718592, 524288);
    gemm256<0><<<dim3(160, 1, 1), 512, 131072, stream>>>(xbf, W, qkv, nullptr,
                                                         4096, 2560, 2048, 2048, 2048, 2560);

    rope_kernel<<<dim3(2048, 2), 256, 0, stream>>>(qkv, cosT, sinT);
    vtrans_kernel<<<dim3(32, 4, 2), 256, 0, stream>>>(qkv, vTb);
    flash_kernel<<<dim3(32, 8, 2), 256, 0, stream>>>(qkv, vTb, attno);

    // h += attn_out @ wo^T  (split-K x2 -> f32 partials, then combine)
    cvt(lwo, W, 4194304);
    gemm256<3><<<dim3(128, 1, 2), 512, 131072, stream>>>(attno, W, nullptr, pbuf,
                                                         4096, 2048, 1024, 2048, 2048, 2048);
    combine_kernel<<<2048, 256, 0, stream>>>(h, pbuf, pbuf + 8388608ull, 2097152);

    // x = rms(h, ln2)
    rms_kernel<true><<<4096, 256, 0, stream>>>(h, ln2 + l * 2048, xbf, nullptr);

    // gate = x @ wg^T ; prod = gelu(gate) * (x @ wu^T)  (in place in gateb)
    cvt(lwg, W, 33554432);
    cvt(lwu, W + 33554432, 33554432);
    gemm256<0><<<dim3(1024, 1, 1), 512, 131072, stream>>>(xbf, W, gateb, nullptr,
                                                          4096, 16384, 2048, 2048, 2048, 16384);
    gemm256<2><<<dim3(1024, 1, 1), 512, 131072, stream>>>(xbf, W + 33554432, gateb, nullptr,
                                                          4096, 16384, 2048, 2048, 2048, 16384);

    // h += prod @ wd^T  (split-K x2 into f32 partials, then combine)
    cvt(lwd, W, 33554432);
    gemm256<3><<<dim3(128, 1, 2), 512, 131072, stream>>>(gateb, W, nullptr, pbuf,
                                                         4096, 2048, 8192, 16384, 16384, 2048);
    combine_kernel<<<2048, 256, 0, stream>>>(h, pbuf, pbuf + 8388608ull, 2097152);
  }

  // final norm (in place, f32 out)
  rms_kernel<false><<<4096, 256, 0, stream>>>(h, nw, nullptr, h);
}

// Round 5
// 3455.200 us; speedup vs baseline: 1.0324x; 1.0324x over previous
//
#include <hip/hip_runtime.h>
#include <cstdint>
#include <cstddef>

// ---------------------------------------------------------------------------
// Gemma 2-layer forward, MI355X. Round 5: m201-style 8-phase GEMM —
//   BM=BN=256, BK=64, 8 waves, 2x64KB LDS dbuf, 4 stage-units/K-tile,
//   one barrier per phase, ledger-derived counted vmcnt, XOR swizzle,
//   lgkmcnt(0)+sched_barrier before MFMA, setprio clusters, XCD swizzle.
// ---------------------------------------------------------------------------

typedef unsigned short u16;
typedef __bf16 bf16x8 __attribute__((ext_vector_type(8)));
typedef float f32x4 __attribute__((ext_vector_type(4)));

#define S_LEN 2048
#define HDIM  2048
#define NHEAD 8
#define HD    256
#define QKV_N 2560
#define ATT_SCALE 0.0625f

__device__ __forceinline__ u16 f2b(float f) {
  union { float f; unsigned u; } x; x.f = f;
  unsigned r = x.u + 0x7FFFu + ((x.u >> 16) & 1u);
  return (u16)(r >> 16);
}
__device__ __forceinline__ float b2f(u16 b) {
  union { unsigned u; float f; } x; x.u = ((unsigned)b) << 16;
  return x.f;
}

typedef __attribute__((address_space(1))) void as1_void;
typedef __attribute__((address_space(3))) void as3_void;
__device__ __forceinline__ void gload_lds16(const void* g, void* l) {
  __builtin_amdgcn_global_load_lds((as1_void*)((void*)g), (as3_void*)l, 16, 0, 0);
}

__device__ __forceinline__ void barrier_raw() {
  __builtin_amdgcn_sched_barrier(0);
  asm volatile("" ::: "memory");
  __builtin_amdgcn_s_barrier();
  asm volatile("" ::: "memory");
  __builtin_amdgcn_sched_barrier(0);
}

__device__ __forceinline__ float gelu_tanh(float x) {
  float t = tanhf(0.7978845608028654f * (x + 0.044715f * x * x * x));
  return 0.5f * x * (1.0f + t);
}

// ---------------------------------------------------------------------------
// f32 -> bf16 conversion (vectorized grid-stride)
// ---------------------------------------------------------------------------
__global__ void cvt_kernel(const float* __restrict__ in, u16* __restrict__ out, int n4) {
  int idx = blockIdx.x * blockDim.x + threadIdx.x;
  int stride = gridDim.x * blockDim.x;
  for (int i = idx; i < n4; i += stride) {
    f32x4 v = reinterpret_cast<const f32x4*>(in)[i];
    unsigned lo = (unsigned)f2b(v[0]) | ((unsigned)f2b(v[1]) << 16);
    unsigned hi = (unsigned)f2b(v[2]) | ((unsigned)f2b(v[3]) << 16);
    uint2 p; p.x = lo; p.y = hi;
    reinterpret_cast<uint2*>(out)[i] = p;
  }
}

// ---------------------------------------------------------------------------
// RMSNorm: one block per row (H=2048, 256 thr * 8 elems). f32 math.
// ---------------------------------------------------------------------------
template<bool OBF>
__launch_bounds__(256)
__global__ void rms_kernel(const float* in, const float* w, u16* obf, float* of) {
  const int row = blockIdx.x;
  const int tid = threadIdx.x;
  const float* x = in + (size_t)row * HDIM;
  f32x4 v0 = reinterpret_cast<const f32x4*>(x)[tid];
  f32x4 v1 = reinterpret_cast<const f32x4*>(x)[tid + 256];
  float ss = v0[0]*v0[0] + v0[1]*v0[1] + v0[2]*v0[2] + v0[3]*v0[3]
           + v1[0]*v1[0] + v1[1]*v1[1] + v1[2]*v1[2] + v1[3]*v1[3];
#pragma unroll
  for (int off = 32; off > 0; off >>= 1) ss += __shfl_xor(ss, off);
  __shared__ float sred[4];
  if ((tid & 63) == 0) sred[tid >> 6] = ss;
  __syncthreads();
  float tot = sred[0] + sred[1] + sred[2] + sred[3];
  float r = rsqrtf(tot * (1.0f / (float)HDIM) + 1e-6f);
  f32x4 w0 = reinterpret_cast<const f32x4*>(w)[tid];
  f32x4 w1 = reinterpret_cast<const f32x4*>(w)[tid + 256];
#pragma unroll
  for (int j = 0; j < 4; ++j) {
    float a = v0[j] * r * (1.0f + w0[j]);
    float b = v1[j] * r * (1.0f + w1[j]);
    if (OBF) {
      obf[(size_t)row * HDIM + tid * 4 + j]        = f2b(a);
      obf[(size_t)row * HDIM + 1024 + tid * 4 + j] = f2b(b);
    } else {
      of[(size_t)row * HDIM + tid * 4 + j]        = a;
      of[(size_t)row * HDIM + 1024 + tid * 4 + j] = b;
    }
  }
}

// ---------------------------------------------------------------------------
// GEMM  C[M,N] = A[M,K] * B[N,K]^T  (bf16 in, f32 acc) — 8-phase m201 port.
// BM=BN=256, BK=64, 8 waves (2Mx4N). LDS: 2 bufs x 64KB:
//   A: [u0: rows 0-127][u1: rows 128-255], 128B rows, slot^=(row&7) swizzle
//   B: [u2: kh0][u3: kh1], 64B rows, slot^=(row&3) swizzle
// 4 phases/K-tile: p=(kh,mh). Per phase: vmcnt -> barrier -> stage 1 unit of
// tile t+1 -> ds_read subtile -> lgkm0+schedbar -> setprio 16 MFMA.
// Wait ledger (steady): p0 vmcnt(2) {t:u3}; p1 (4) {t:u3,t+1:u0};
//   p2 (4) {t+1:u0,u1} (forces t:u3 = B-kh1, needed now); p3 (6) {t+1:u0,u1,u2}.
// Tail (no stage): [2,2,0,0].  All reads drained (lgkm0) before each wave's
// next barrier => stage-after-barrier is WAR-safe cross-wave.
// EPI 0: Cb=bf16   1: Cf+=acc   2: Cb=gelu(Cb)*acc   3: Cf[z*M*N+idx]=acc
// Requires M%256==0, N%256==0, Ks%64==0, lda/ldb%8==0.
// ---------------------------------------------------------------------------
#define PH_COMPUTE(KH, MH, FB, READB)                                         \
  {                                                                           \
    bf16x8 fa0 = *reinterpret_cast<const bf16x8*>(cb + aoff[KH][(MH)*4+0]);   \
    bf16x8 fa1 = *reinterpret_cast<const bf16x8*>(cb + aoff[KH][(MH)*4+1]);   \
    bf16x8 fa2 = *reinterpret_cast<const bf16x8*>(cb + aoff[KH][(MH)*4+2]);   \
    bf16x8 fa3 = *reinterpret_cast<const bf16x8*>(cb + aoff[KH][(MH)*4+3]);   \
    if (READB) {                                                              \
      FB[0] = *reinterpret_cast<const bf16x8*>(cb + boff[KH][0]);             \
      FB[1] = *reinterpret_cast<const bf16x8*>(cb + boff[KH][1]);             \
      FB[2] = *reinterpret_cast<const bf16x8*>(cb + boff[KH][2]);             \
      FB[3] = *reinterpret_cast<const bf16x8*>(cb + boff[KH][3]);             \
    }                                                                         \
    asm volatile("s_waitcnt lgkmcnt(0)" ::: "memory");                        \
    __builtin_amdgcn_sched_barrier(0);                                        \
    __builtin_amdgcn_s_setprio(1);                                            \
    _Pragma("unroll")                                                         \
    for (int nf = 0; nf < 4; ++nf) {                                          \
      acc[(MH)*4+0][nf] = __builtin_amdgcn_mfma_f32_16x16x32_bf16(fa0, FB[nf], acc[(MH)*4+0][nf], 0,0,0); \
      acc[(MH)*4+1][nf] = __builtin_amdgcn_mfma_f32_16x16x32_bf16(fa1, FB[nf], acc[(MH)*4+1][nf], 0,0,0); \
      acc[(MH)*4+2][nf] = __builtin_amdgcn_mfma_f32_16x16x32_bf16(fa2, FB[nf], acc[(MH)*4+2][nf], 0,0,0); \
      acc[(MH)*4+3][nf] = __builtin_amdgcn_mfma_f32_16x16x32_bf16(fa3, FB[nf], acc[(MH)*4+3][nf], 0,0,0); \
    }                                                                         \
    __builtin_amdgcn_s_setprio(0);                                            \
  }

template<int EPI>
__launch_bounds__(512, 2)
__global__ void gemm256p(const u16* __restrict__ A, const u16* __restrict__ B,
                         u16* Cb, float* Cf, int M, int N, int Ks,
                         int lda, int ldb, int ldc) {
  extern __shared__ char smem[];   // 2 bufs x 64KB
  const int tid = threadIdx.x;
  const int lane = tid & 63, w = tid >> 6;
  const int l16 = lane & 15, lhi = lane >> 4;
  const int wr = w >> 2, wc = w & 3;

  // bijective XCD swizzle (m204), column-major tile map
  const int nwg = gridDim.x, bid = blockIdx.x;
  const int q = nwg >> 3, rm = nwg & 7, xc = bid & 7, li = bid >> 3;
  const int swz = (xc < rm ? xc * (q + 1) : rm * (q + 1) + (xc - rm) * q) + li;
  const int MT = M >> 8;
  const int m0 = (swz % MT) << 8;
  const int n0 = (swz / MT) << 8;

  const int kbase = blockIdx.z * Ks;
  const int NT = Ks >> 6;   // BK = 64

  // stage sources (pre-swizzled per lane; LDS dest = wave-uniform + lane*16)
  const u16* srcU[4][2];
#pragma unroll
  for (int j = 0; j < 2; ++j) {
    int o = j * 8192 + tid * 16;
    {
      int r = o >> 7, s = (o >> 4) & 7;
      int ks = (s ^ (r & 7)) << 3;
      srcU[0][j] = A + (size_t)(m0 + r) * lda + kbase + ks;
      srcU[1][j] = A + (size_t)(m0 + 128 + r) * lda + kbase + ks;
    }
    {
      int r = o >> 6, s = (o >> 4) & 3;
      int ks = (s ^ (r & 3)) << 3;
      srcU[2][j] = B + (size_t)(n0 + r) * ldb + kbase + ks;
      srcU[3][j] = B + (size_t)(n0 + r) * ldb + kbase + 32 + ks;
    }
  }

  auto stage = [&](int t, int u) {
    char* bb = smem + ((size_t)(t & 1) << 16) + (u << 14) + w * 1024;
    gload_lds16(srcU[u][0] + t * 64, bb);
    gload_lds16(srcU[u][1] + t * 64, bb + 8192);
  };

  // swizzled frag read offsets (buffer-relative)
  int aoff[2][8], boff[2][4];
#pragma unroll
  for (int kh = 0; kh < 2; ++kh) {
#pragma unroll
    for (int mf = 0; mf < 8; ++mf)
      aoff[kh][mf] = wr * 16384 + (mf * 16 + l16) * 128
                   + (((kh * 4 + lhi) ^ (l16 & 7)) << 4);
#pragma unroll
    for (int nf = 0; nf < 4; ++nf)
      boff[kh][nf] = 32768 + kh * 16384 + (wc * 64 + nf * 16 + l16) * 64
                   + ((lhi ^ (l16 & 3)) << 4);
  }

  f32x4 acc[8][4] = {};
  bf16x8 fb0[4], fb1[4];

  // prologue: stage all 4 units of tile 0
  stage(0, 0); stage(0, 1); stage(0, 2); stage(0, 3);

  for (int t = 0; t < NT; ++t) {
    const char* cb = smem + ((size_t)(t & 1) << 16);
    const bool st = (t + 1) < NT;

    // phase 0: (kh0, mh0) + B-kh0
    asm volatile("s_waitcnt vmcnt(2)" ::: "memory");
    barrier_raw();
    if (st) stage(t + 1, 0);
    PH_COMPUTE(0, 0, fb0, true);

    // phase 1: (kh0, mh1)
    if (st) asm volatile("s_waitcnt vmcnt(4)" ::: "memory");
    else    asm volatile("s_waitcnt vmcnt(2)" ::: "memory");
    barrier_raw();
    if (st) stage(t + 1, 1);
    PH_COMPUTE(0, 1, fb0, false);

    // phase 2: (kh1, mh0) + B-kh1  (vmcnt forces t:u3 = B-kh1)
    if (st) asm volatile("s_waitcnt vmcnt(4)" ::: "memory");
    else    asm volatile("s_waitcnt vmcnt(0)" ::: "memory");
    barrier_raw();
    if (st) stage(t + 1, 2);
    PH_COMPUTE(1, 0, fb1, true);

    // phase 3: (kh1, mh1)
    if (st) asm volatile("s_waitcnt vmcnt(6)" ::: "memory");
    else    asm volatile("s_waitcnt vmcnt(0)" ::: "memory");
    barrier_raw();
    if (st) stage(t + 1, 3);
    PH_COMPUTE(1, 1, fb1, false);
  }

#pragma unroll
  for (int mf = 0; mf < 8; ++mf)
#pragma unroll
    for (int nf = 0; nf < 4; ++nf)
#pragma unroll
      for (int rr = 0; rr < 4; ++rr) {
        int row = m0 + wr * 128 + mf * 16 + lhi * 4 + rr;
        int col = n0 + wc * 64 + nf * 16 + l16;
        size_t idx = (size_t)row * ldc + col;
        float v = acc[mf][nf][rr];
        if (EPI == 0)      Cb[idx] = f2b(v);
        else if (EPI == 1) Cf[idx] += v;
        else if (EPI == 2) { float g = b2f(Cb[idx]); Cb[idx] = f2b(gelu_tanh(g) * v); }
        else               Cf[(size_t)blockIdx.z * ((size_t)M * N) + idx] = v;
      }
}

// h += p0 + p1 (split-K combine), f32x4 grid-stride
__global__ void combine_kernel(float* __restrict__ h, const float* __restrict__ p0,
                               const float* __restrict__ p1, int n4) {
  int idx = blockIdx.x * blockDim.x + threadIdx.x;
  int stride = gridDim.x * blockDim.x;
  for (int i = idx; i < n4; i += stride) {
    f32x4 a = reinterpret_cast<f32x4*>(h)[i];
    f32x4 b = reinterpret_cast<const f32x4*>(p0)[i];
    f32x4 c = reinterpret_cast<const f32x4*>(p1)[i];
    a = a + b + c;
    reinterpret_cast<f32x4*>(h)[i] = a;
  }
}

// ---------------------------------------------------------------------------
// RoPE in place on fused qkv buffer [4096][2560]
// ---------------------------------------------------------------------------
__global__ void rope_kernel(u16* qkv, const float* __restrict__ cosT, const float* __restrict__ sinT) {
  const int s = blockIdx.x, b = blockIdx.y;
  const size_t base = (size_t)(b * S_LEN + s) * QKV_N;
  for (int i = threadIdx.x; i < 9 * 128; i += 256) {
    int hh = i >> 7, d = i & 127;
    size_t off = base + (hh < 8 ? hh * 256 : 2048) + d;
    float x1 = b2f(qkv[off]), x2 = b2f(qkv[off + 128]);
    float c = cosT[s * 128 + d], sn = sinT[s * 128 + d];
    qkv[off]       = f2b(x1 * c - x2 * sn);
    qkv[off + 128] = f2b(x1 * sn + x2 * c);
  }
}

// ---------------------------------------------------------------------------
// V transpose: vT[b][d][s] <- qkv[b*S+s][2304+d]
// ---------------------------------------------------------------------------
__global__ void vtrans_kernel(const u16* __restrict__ qkv, u16* __restrict__ vT) {
  __shared__ u16 t[64][65];
  const int s0 = blockIdx.x * 64, d0 = blockIdx.y * 64, b = blockIdx.z;
  for (int i = threadIdx.x; i < 4096; i += 256) {
    int r = i >> 6, c = i & 63;
    t[r][c] = qkv[(size_t)(b * S_LEN + s0 + r) * QKV_N + 2304 + d0 + c];
  }
  __syncthreads();
  for (int i = threadIdx.x; i < 4096; i += 256) {
    int r = i >> 6, c = i & 63;
    vT[(size_t)(b * HD + d0 + r) * S_LEN + s0 + c] = t[c][r];
  }
}

// ---------------------------------------------------------------------------
// Causal flash attention (MQA, NKV=1), 64 q-rows/block, 4 waves.
// ---------------------------------------------------------------------------
__launch_bounds__(256)
__global__ void flash_kernel(const u16* __restrict__ qkv, const u16* __restrict__ vT,
                             u16* __restrict__ outp) {
  const int qt = blockIdx.x, hh = blockIdx.y, b = blockIdx.z;
  const int tid = threadIdx.x, lane = tid & 63, w = tid >> 6;
  const int l16 = lane & 15, lhi = lane >> 4;
  __shared__ alignas(16) u16 p_lds[4][16][64];

  bf16x8 aq[8];
  {
    const u16* qp = qkv + (size_t)(b * S_LEN + qt * 64 + w * 16 + l16) * QKV_N + hh * HD + lhi * 8;
#pragma unroll
    for (int kf = 0; kf < 8; ++kf)
      aq[kf] = *reinterpret_cast<const bf16x8*>(qp + kf * 32);
  }
  f32x4 oacc[16] = {};
  float mrow[4] = {-1e30f, -1e30f, -1e30f, -1e30f};
  float lrow[4] = {0.f, 0.f, 0.f, 0.f};
  const int rowg0 = qt * 64 + w * 16 + lhi * 4;

  const int ntiles = qt + 1;
  for (int t = 0; t < ntiles; ++t) {
    const int j0 = t * 64;
    f32x4 sacc[4] = {};
    {
      const u16* kb = qkv + (size_t)(b * S_LEN + j0) * QKV_N + HDIM + lhi * 8;
#pragma unroll
      for (int nf = 0; nf < 4; ++nf) {
        const u16* kp = kb + (size_t)(nf * 16 + l16) * QKV_N;
#pragma unroll
        for (int kf = 0; kf < 8; ++kf) {
          bf16x8 bk = *reinterpret_cast<const bf16x8*>(kp + kf * 32);
          sacc[nf] = __builtin_amdgcn_mfma_f32_16x16x32_bf16(aq[kf], bk, sacc[nf], 0, 0, 0);
        }
      }
    }
    float sval[4][4];
    float tm[4] = {-1e30f, -1e30f, -1e30f, -1e30f};
#pragma unroll
    for (int nf = 0; nf < 4; ++nf) {
      int colg = j0 + nf * 16 + l16;
#pragma unroll
      for (int r = 0; r < 4; ++r) {
        float sv = sacc[nf][r] * ATT_SCALE;
        if (colg > rowg0 + r) sv = -1e30f;
        sval[nf][r] = sv;
        tm[r] = fmaxf(tm[r], sv);
      }
    }
#pragma unroll
    for (int off = 1; off < 16; off <<= 1)
#pragma unroll
      for (int r = 0; r < 4; ++r) tm[r] = fmaxf(tm[r], __shfl_xor(tm[r], off));

    float alpha[4], psum[4] = {0.f, 0.f, 0.f, 0.f};
#pragma unroll
    for (int r = 0; r < 4; ++r) {
      float mn = fmaxf(mrow[r], tm[r]);
      alpha[r] = __expf(mrow[r] - mn);
      mrow[r] = mn;
    }
#pragma unroll
    for (int nf = 0; nf < 4; ++nf)
#pragma unroll
      for (int r = 0; r < 4; ++r) {
        float p = __expf(sval[nf][r] - mrow[r]);
        psum[r] += p;
        p_lds[w][lhi * 4 + r][nf * 16 + l16] = f2b(p);
      }
#pragma unroll
    for (int off = 1; off < 16; off <<= 1)
#pragma unroll
      for (int r = 0; r < 4; ++r) psum[r] += __shfl_xor(psum[r], off);
#pragma unroll
    for (int r = 0; r < 4; ++r) lrow[r] = lrow[r] * alpha[r] + psum[r];
#pragma unroll
    for (int nf2 = 0; nf2 < 16; ++nf2)
#pragma unroll
      for (int r = 0; r < 4; ++r) oacc[nf2][r] *= alpha[r];

#pragma unroll
    for (int kf2 = 0; kf2 < 2; ++kf2) {
      bf16x8 pa = *reinterpret_cast<const bf16x8*>(&p_lds[w][l16][kf2 * 32 + lhi * 8]);
      const u16* vb = vT + (size_t)(b * HD + l16) * S_LEN + j0 + kf2 * 32 + lhi * 8;
#pragma unroll
      for (int nf2 = 0; nf2 < 16; ++nf2) {
        bf16x8 bv = *reinterpret_cast<const bf16x8*>(vb + (size_t)(nf2 * 16) * S_LEN);
        oacc[nf2] = __builtin_amdgcn_mfma_f32_16x16x32_bf16(pa, bv, oacc[nf2], 0, 0, 0);
      }
    }
  }

  float inv[4];
#pragma unroll
  for (int r = 0; r < 4; ++r) inv[r] = 1.0f / lrow[r];
#pragma unroll
  for (int nf2 = 0; nf2 < 16; ++nf2)
#pragma unroll
    for (int r = 0; r < 4; ++r) {
      size_t idx = (size_t)(b * S_LEN + rowg0 + r) * HDIM + hh * HD + nf2 * 16 + l16;
      outp[idx] = f2b(oacc[nf2][r] * inv[r]);
    }
}

// ---------------------------------------------------------------------------
// Host orchestration
// ---------------------------------------------------------------------------
extern "C" void kernel_launch(void* const* d_in, const int* in_sizes, int n_in,
                              void* d_out, int out_size, void* d_ws, size_t ws_size,
                              hipStream_t stream) {
  const float* hidden = (const float*)d_in[0];
  const float* cosT   = (const float*)d_in[1];
  const float* sinT   = (const float*)d_in[2];
  const float* wq  = (const float*)d_in[6];
  const float* wk  = (const float*)d_in[7];
  const float* wv  = (const float*)d_in[8];
  const float* wo  = (const float*)d_in[9];
  const float* wg  = (const float*)d_in[10];
  const float* wu  = (const float*)d_in[11];
  const float* wd  = (const float*)d_in[12];
  const float* ln1 = (const float*)d_in[13];
  const float* ln2 = (const float*)d_in[14];
  const float* nw  = (const float*)d_in[15];
  float* h = (float*)d_out;

  // ws layout (u16 elems): W 67.1M | xbf 8.4M | qkv 10.5M | vT 1.05M | attno 8.4M | gate 67.1M
  u16* W     = (u16*)d_ws;
  u16* xbf   = W + 67108864ull;
  u16* qkv   = xbf + 8388608ull;
  u16* vTb   = qkv + 10485760ull;
  u16* attno = vTb + 1048576ull;
  u16* gateb = attno + 8388608ull;
  float* pbuf = (float*)(W + 33554432ull);  // split-K partials (2 x 8.4M f32)

  hipFuncSetAttribute(reinterpret_cast<const void*>(gemm256p<0>), hipFuncAttributeMaxDynamicSharedMemorySize, 131072);
  hipFuncSetAttribute(reinterpret_cast<const void*>(gemm256p<1>), hipFuncAttributeMaxDynamicSharedMemorySize, 131072);
  hipFuncSetAttribute(reinterpret_cast<const void*>(gemm256p<2>), hipFuncAttributeMaxDynamicSharedMemorySize, 131072);
  hipFuncSetAttribute(reinterpret_cast<const void*>(gemm256p<3>), hipFuncAttributeMaxDynamicSharedMemorySize, 131072);

  hipMemcpyAsync(h, hidden, sizeof(float) * 8388608ull, hipMemcpyDeviceToDevice, stream);

  auto cvt = [&](const float* src, u16* dst, long n) {
    int n4 = (int)(n >> 2);
    int blocks = (n4 + 255) / 256;
    if (blocks > 2048) blocks = 2048;
    cvt_kernel<<<blocks, 256, 0, stream>>>(src, dst, n4);
  };

  for (int l = 0; l < 2; ++l) {
    const float* lwq = wq + (size_t)l * 2048 * 2048;
    const float* lwk = wk + (size_t)l * 256 * 2048;
    const float* lwv = wv + (size_t)l * 256 * 2048;
    const float* lwo = wo + (size_t)l * 2048 * 2048;
    const float* lwg = wg + (size_t)l * 16384 * 2048;
    const float* lwu = wu + (size_t)l * 16384 * 2048;
    const float* lwd = wd + (size_t)l * 2048 * 16384;

    // x = rms(h, ln1)
    rms_kernel<true><<<4096, 256, 0, stream>>>(h, ln1 + l * 2048, xbf, nullptr);

    // fused qkv projection: W rows = [wq(2048) | wk(256) | wv(256)]
    cvt(lwq, W, 4194304);
    cvt(lwk, W + 4194304, 524288);
    cvt(lwv, W + 4718592, 524288);
    gemm256p<0><<<dim3(160, 1, 1), 512, 131072, stream>>>(xbf, W, qkv, nullptr,
                                                          4096, 2560, 2048, 2048, 2048, 2560);

    rope_kernel<<<dim3(2048, 2), 256, 0, stream>>>(qkv, cosT, sinT);
    vtrans_kernel<<<dim3(32, 4, 2), 256, 0, stream>>>(qkv, vTb);
    flash_kernel<<<dim3(32, 8, 2), 256, 0, stream>>>(qkv, vTb, attno);

    // h += attn_out @ wo^T  (split-K x2 -> f32 partials, then combine)
    cvt(lwo, W, 4194304);
    gemm256p<3><<<dim3(128, 1, 2), 512, 131072, stream>>>(attno, W, nullptr, pbuf,
                                                          4096, 2048, 1024, 2048, 2048, 2048);
    combine_kernel<<<2048, 256, 0, stream>>>(h, pbuf, pbuf + 8388608ull, 2097152);

    // x = rms(h, ln2)
    rms_kernel<true><<<4096, 256, 0, stream>>>(h, ln2 + l * 2048, xbf, nullptr);

    // gate = x @ wg^T ; prod = gelu(gate) * (x @ wu^T)  (in place in gateb)
    cvt(lwg, W, 33554432);
    cvt(lwu, W + 33554432, 33554432);
    gemm256p<0><<<dim3(1024, 1, 1), 512, 131072, stream>>>(xbf, W, gateb, nullptr,
                                                           4096, 16384, 2048, 2048, 2048, 16384);
    gemm256p<2><<<dim3(1024, 1, 1), 512, 131072, stream>>>(xbf, W + 33554432, gateb, nullptr,
                                                           4096, 16384, 2048, 2048, 2048, 16384);

    // h += prod @ wd^T  (split-K x2 into f32 partials, then combine)
    cvt(lwd, W, 33554432);
    gemm256p<3><<<dim3(128, 1, 2), 512, 131072, stream>>>(gateb, W, nullptr, pbuf,
                                                          4096, 2048, 8192, 16384, 16384, 2048);
    combine_kernel<<<2048, 256, 0, stream>>>(h, pbuf, pbuf + 8388608ull, 2097152);
  }

  // final norm (in place, f32 out)
  rms_kernel<false><<<4096, 256, 0, stream>>>(h, nw, nullptr, h);
}